// Round 5
// baseline (146.247 us; speedup 1.0000x reference)
//
#include <hip/hip_runtime.h>
#include <hip/hip_fp16.h>
#include <math.h>

#define N_NODES 10000
#define N_EDGES 160000
#define B_ 8
#define D_ 64
#define BD 512          // B_*D_
#define CAP 48          // max edges kept per node; P(Poisson(16) >= 48) ~ 6e-11
#define CAPR 56         // bucket row stride

typedef _Float16 f16x8 __attribute__((ext_vector_type(8)));
typedef float f32x4 __attribute__((ext_vector_type(4)));
typedef float f4v __attribute__((ext_vector_type(4)));
typedef unsigned int u32;

union HU { _Float16 f; unsigned short u; };
union HC { u32 u; __half2 h; };

// ---------------- fused prep: per-block edge-scatter + MFMA proj (1250 blocks) --------
// Each block: (a) scatters 128 edges into buckets -- bucket[d*CAPR+pos] =
// src | (half(dist*log2e)<<16), counts via atomic. (b) projects 64 state rows:
// P[m][c] = sum_k state[m][k]*W[(c>=64?64:0)+k][c&63].
// NEW this round: G and Pd are NODE-MAJOR (node block = 8 slices x 64 = 2 KB
// contiguous), so the aggregate wave gathers one edge's full (all-b, all-d) block
// with two contiguous 1 KB loads:
//   row m = node*8+b -> G words [node*512 + b*64 + q*4 .. +3] = {p01,p23,x01,x23}
//                       Pd[node*512 + b*64 + d] = half(p_dst)
__global__ void __launch_bounds__(256, 4) prep_kernel(
    const int* __restrict__ src, const int* __restrict__ dst,
    const float* __restrict__ dist, int* __restrict__ counts, u32* __restrict__ bucket,
    const float* __restrict__ state, const float* __restrict__ weight,
    u32* __restrict__ G, __half* __restrict__ Pd) {
    __shared__ _Float16 At[64 * 72];          // 9 KB  (fp16 state tile, also x source)
    __shared__ char smemB[128 * 72 * 2];      // 18.4 KB: Bt, then Ps2+Ps
    _Float16* Bt = (_Float16*)smemB;                        // [128][72]
    unsigned short* Ps2 = (unsigned short*)smemB;           // [64][68] p_src
    unsigned short* Ps  = (unsigned short*)(smemB + 8704);  // [64][64] p_dst
    int bid = blockIdx.x;
    int tid = threadIdx.x;

    // ---- edge scatter: 128 edges per block (1250*128 == N_EDGES) ----
    int s_e, d_e; float di_e;
    bool do_edge = tid < 128;
    if (do_edge) {
        int e = bid * 128 + tid;
        s_e = src[e];
        d_e = dst[e];
        di_e = dist[e];
    }

    // ---- proj staging ----
    int row0 = bid * 64;
    int wave = tid >> 6, lane = tid & 63;
    int quad = lane >> 4, m16 = lane & 15;
    int m_loc = wave * 16 + m16;

    // stage state tile (read-once stream) -> fp16 LDS
    const f4v* st4 = (const f4v*)(state + (size_t)row0 * 64);
    for (int i = tid; i < 1024; i += 256) {
        int r = i >> 4, c4 = (i & 15) << 2;
        f4v v = __builtin_nontemporal_load(&st4[i]);
        union { short4 s; _Float16 h[4]; } u;
        u.h[0] = (_Float16)v[0]; u.h[1] = (_Float16)v[1];
        u.h[2] = (_Float16)v[2]; u.h[3] = (_Float16)v[3];
        *(short4*)&At[r * 72 + c4] = u.s;
    }
    // stage weight (32 KB, L2-resident across blocks) transposed -> Bt[n][k]
    const f4v* w4 = (const f4v*)weight;
    for (int i = tid; i < 2048; i += 256) {
        int r = i >> 4, c4 = (i & 15) << 2;    // r in [0,128): r = h*64+k
        f4v v = w4[i];
        int h = r >> 6, k = r & 63;
        int nb = h * 64 + c4;
        Bt[(nb + 0) * 72 + k] = (_Float16)v[0];
        Bt[(nb + 1) * 72 + k] = (_Float16)v[1];
        Bt[(nb + 2) * 72 + k] = (_Float16)v[2];
        Bt[(nb + 3) * 72 + k] = (_Float16)v[3];
    }

    // complete the edge scatter (atomic + scattered 4B store) while LDS fills drain
    if (do_edge) {
        int pos = atomicAdd(&counts[d_e], 1);
        if (pos < CAP) {
            unsigned short hd = __half_as_ushort(__float2half_rn(di_e * 1.44269504f));
            bucket[d_e * CAPR + pos] = (u32)s_e | ((u32)hd << 16);
        }
    }
    __syncthreads();

    // hoist all B-fragments into registers; Bt LDS becomes dead after this
    f16x8 bf0[8], bf1[8];
#pragma unroll
    for (int tcol = 0; tcol < 8; tcol++) {
        int n = tcol * 16 + m16;
        bf0[tcol] = *(const f16x8*)&Bt[n * 72 + quad * 8];
        bf1[tcol] = *(const f16x8*)&Bt[n * 72 + 32 + quad * 8];
    }
    f16x8 a0 = *(const f16x8*)&At[m_loc * 72 + quad * 8];
    f16x8 a1 = *(const f16x8*)&At[m_loc * 72 + 32 + quad * 8];
    __syncthreads();   // everyone done with Bt; reuse as Ps2/Ps

#pragma unroll
    for (int tcol = 0; tcol < 8; tcol++) {
        int n = tcol * 16 + m16;
        f32x4 acc = {0.f, 0.f, 0.f, 0.f};
        acc = __builtin_amdgcn_mfma_f32_16x16x32_f16(a0, bf0[tcol], acc, 0, 0, 0);
        acc = __builtin_amdgcn_mfma_f32_16x16x32_f16(a1, bf1[tcol], acc, 0, 0, 0);
#pragma unroll
        for (int r = 0; r < 4; r++) {
            int ml = wave * 16 + quad * 4 + r;
            unsigned short ph = __half_as_ushort(__float2half_rn(acc[r]));
            if (tcol < 4) Ps2[ml * 68 + n] = ph;
            else          Ps[ml * 64 + (n - 64)] = ph;
        }
    }
    __syncthreads();

    // coalesced G write, node-major planar-quad: float4 per (row, quad) = {p01,p23,x01,x23}
    const u32* Ps2w = (const u32*)Ps2;
    const u32* Atw = (const u32*)At;
    for (int i = tid; i < 1024; i += 256) {
        int row = i >> 4, q = i & 15;
        int m = row0 + row;
        size_t base = (size_t)(m >> 3) * 512 + (size_t)(m & 7) * 64;   // node*512 + b*64
        u32 p01 = Ps2w[row * 34 + q * 2];
        u32 p23 = Ps2w[row * 34 + q * 2 + 1];
        u32 x01 = Atw[row * 36 + q * 2];
        u32 x23 = Atw[row * 36 + q * 2 + 1];
        float4 v = make_float4(__uint_as_float(p01), __uint_as_float(p23),
                               __uint_as_float(x01), __uint_as_float(x23));
        *(float4*)&G[base + q * 4] = v;
    }
    // coalesced Pd write, node-major: 512 float4 (8 lanes = one row's 128 B)
    for (int i = tid; i < 512; i += 256) {
        int row = i >> 3, seg = i & 7;
        int m = row0 + row;
        size_t base = (size_t)(m >> 3) * 512 + (size_t)(m & 7) * 64;   // node*512 + b*64
        *(float4*)&Pd[base + seg * 8] = *(const float4*)&Ps[row * 64 + seg * 8];
    }
}

// ---------------- fused segment-softmax + aggregate: 1 node per WAVE --------------
// NEW decomposition: wave w handles node n = blockIdx*4 + w across ALL 8 slices.
// Lane l owns G words [l*4 .. l*4+3] (slice l>>4, quad l&15) and [+256] (slice
// (l>>4)+4) of the node-major 2 KB node block. Per edge: one uniform-address record
// load (HW broadcast) + two fully-contiguous 1 KB wave gathers + 8 element-instances
// of math per lane. No cross-lane reduction, no padding, exact cnt loop; out written
// by all 64 lanes fully coalesced.
__global__ void __launch_bounds__(256) gat_aggregate(
    const u32* __restrict__ G,          // node-major [node][b][16 quads][4 words]
    const __half* __restrict__ Pds,     // node-major [node][b][64]
    const int* __restrict__ counts,
    const u32* __restrict__ bucket,
    float* __restrict__ out) {
    int wave = threadIdx.x >> 6;
    int lane = threadIdx.x & 63;
    int n = (blockIdx.x << 2) + wave;   // 2500 blocks x 4 waves = 10000 nodes

    int offA = lane * 4;                // word/half/float offset: slice lane>>4, quad lane&15
    int offB = offA + 256;              // slice (lane>>4)+4, same quad

    int cnt = counts[n]; if (cnt > CAP) cnt = CAP;
    const u32* ep = bucket + n * CAPR;

    union { double d; __half2 h[2]; } pdA, pdB;
    pdA.d = *(const double*)(Pds + (size_t)n * 512 + offA);
    pdB.d = *(const double*)(Pds + (size_t)n * 512 + offB);

    const __half2 c06 = __float2half2_rn(0.6f);
    const __half2 c04 = __float2half2_rn(0.4f);
    __half2 zero = __float2half2_rn(0.f);
    __half2 lA0 = zero, lA1 = zero, oA0 = zero, oA1 = zero;
    __half2 lB0 = zero, lB1 = zero, oB0 = zero, oB1 = zero;

    // leaky_relu(0.2) -> *dist(log2e-scaled) -> exp2, all fp16
    auto lrexp = [&](__half2 z, __half2 dd) -> __half2 {
        HC zz, az; zz.h = z;
        az.u = zz.u & 0x7fff7fffu;                       // |z|
        __half2 lk = __hfma2(az.h, c04, __hmul2(z, c06));
        __half2 aa = __hmul2(lk, dd);
        return __halves2half2(hexp2(__low2half(aa)), hexp2(__high2half(aa)));
    };

    auto body = [&](float4 g1, float4 g2, __half2 dd) {
        union { float4 f; __half2 h[4]; } u1, u2; u1.f = g1; u2.f = g2;
        __half2 e;
        e = lrexp(__hadd2(u1.h[0], pdA.h[0]), dd); lA0 = __hadd2(lA0, e); oA0 = __hfma2(e, u1.h[2], oA0);
        e = lrexp(__hadd2(u1.h[1], pdA.h[1]), dd); lA1 = __hadd2(lA1, e); oA1 = __hfma2(e, u1.h[3], oA1);
        e = lrexp(__hadd2(u2.h[0], pdB.h[0]), dd); lB0 = __hadd2(lB0, e); oB0 = __hfma2(e, u2.h[2], oB0);
        e = lrexp(__hadd2(u2.h[1], pdB.h[1]), dd); lB1 = __hadd2(lB1, e); oB1 = __hfma2(e, u2.h[3], oB1);
    };

    // 2 edges per iteration: both records + all 4 gathers issued before either body,
    // so the two edges' L2 chains overlap; all branches wave-uniform.
    for (int j = 0; j < cnt; j += 2) {
        u32 ra = ep[j];                       // uniform address -> HW broadcast
        bool two = (j + 1) < cnt;             // wave-uniform
        u32 rb = two ? ep[j + 1] : 0u;
        const u32* pa = G + (size_t)(ra & 0xffffu) * 512;
        float4 ga1 = *(const float4*)(pa + offA);
        float4 ga2 = *(const float4*)(pa + offB);
        float4 gb1, gb2;
        if (two) {
            const u32* pb = G + (size_t)(rb & 0xffffu) * 512;
            gb1 = *(const float4*)(pb + offA);
            gb2 = *(const float4*)(pb + offB);
        }
        __half ha = __ushort_as_half((unsigned short)(ra >> 16));
        body(ga1, ga2, __halves2half2(ha, ha));
        if (two) {
            __half hb = __ushort_as_half((unsigned short)(rb >> 16));
            body(gb1, gb2, __halves2half2(hb, hb));
        }
    }

    float* op = out + (size_t)n * BD;
    float4 rA, rB;
    if (cnt > 0) {
        rA.x = fmaxf(__low2float(oA0)  * __builtin_amdgcn_rcpf(__low2float(lA0)),  0.f);
        rA.y = fmaxf(__high2float(oA0) * __builtin_amdgcn_rcpf(__high2float(lA0)), 0.f);
        rA.z = fmaxf(__low2float(oA1)  * __builtin_amdgcn_rcpf(__low2float(lA1)),  0.f);
        rA.w = fmaxf(__high2float(oA1) * __builtin_amdgcn_rcpf(__high2float(lA1)), 0.f);
        rB.x = fmaxf(__low2float(oB0)  * __builtin_amdgcn_rcpf(__low2float(lB0)),  0.f);
        rB.y = fmaxf(__high2float(oB0) * __builtin_amdgcn_rcpf(__high2float(lB0)), 0.f);
        rB.z = fmaxf(__low2float(oB1)  * __builtin_amdgcn_rcpf(__low2float(lB1)),  0.f);
        rB.w = fmaxf(__high2float(oB1) * __builtin_amdgcn_rcpf(__high2float(lB1)), 0.f);
    } else {
        rA = make_float4(0.f, 0.f, 0.f, 0.f);
        rB = rA;
    }
    *(float4*)(op + offA) = rA;     // 64 lanes x 16B contiguous = 1 KB
    *(float4*)(op + offB) = rB;
}

extern "C" void kernel_launch(void* const* d_in, const int* in_sizes, int n_in,
                              void* d_out, int out_size, void* d_ws, size_t ws_size,
                              hipStream_t stream) {
    const float* state  = (const float*)d_in[0];
    // d_in[1] = feature (unused by the math)
    const float* weight = (const float*)d_in[2];
    const int*   src    = (const int*)d_in[3];
    const int*   dst    = (const int*)d_in[4];
    const float* dist   = (const float*)d_in[5];

    // workspace layout (16B-aligned head first): total ~33 MB
    u32*    G      = (u32*)d_ws;                            // N*512 u32 = 20.48 MB
    __half* Pd     = (__half*)(G + (size_t)N_NODES * 512);  // N*512 half = 10.24 MB
    u32*    bucket = (u32*)(Pd + (size_t)N_NODES * 512);    // N*CAPR u32 = 2.24 MB
    int*    counts = (int*)(bucket + (size_t)N_NODES * CAPR); // N ints (contiguous after bucket)

    // one memset zeroes bucket (pad records decode as {src=0, hd=0}) and counts
    hipMemsetAsync(bucket, 0, ((size_t)N_NODES * CAPR + N_NODES) * sizeof(u32), stream);
    prep_kernel<<<1250, 256, 0, stream>>>(src, dst, dist, counts, bucket,
                                          state, weight, G, Pd);
    gat_aggregate<<<2500, 256, 0, stream>>>(G, Pd, counts, bucket, (float*)d_out);
}

// Round 7
// 141.759 us; speedup vs baseline: 1.0317x; 1.0317x over previous
//
#include <hip/hip_runtime.h>
#include <hip/hip_fp16.h>
#include <math.h>

#define N_NODES 10000
#define N_EDGES 160000
#define B_ 8
#define D_ 64
#define BD 512          // B_*D_
#define CAP 48          // max edges kept per node; P(Poisson(16) >= 48) ~ 6e-11
#define CAPR 56         // bucket row stride

typedef _Float16 f16x8 __attribute__((ext_vector_type(8)));
typedef float f32x4 __attribute__((ext_vector_type(4)));
typedef float f4v __attribute__((ext_vector_type(4)));
typedef unsigned int u32;

union HU { _Float16 f; unsigned short u; };
union HC { u32 u; __half2 h; };

// ---------------- fused prep: per-block edge-scatter + MFMA proj (1250 blocks) --------
// Each block: (a) scatters 128 edges into buckets -- bucket[d*CAPR+pos] =
// src | (half(dist*log2e)<<16), counts via atomic. (b) projects 64 state rows:
// P[m][c] = sum_k state[m][k]*W[(c>=64?64:0)+k][c&63].
// G and Pd are SLICE-PAIR-MAJOR: bp = b>>1 in {0..3}, sb = b&1.
//   row m = node*8+b -> G words [bp*N*128 + node*128 + sb*64 + q*4 .. +3]
//                          = {p01,p23,x01,x23} for d-quad q
//                       Pd[bp*N*128 + node*128 + sb*64 + d] = half(p_dst)
// Rationale: per-bp gather working set = 5.12 MB, mostly resident in one XCD's 4 MB
// L2 (bp<->XCD affinity via bid%4 in the aggregate grid), while a wave still owns a
// (node, 2-slice) output block -> reduction-free accumulation, 1 KB coalesced gathers.
__global__ void __launch_bounds__(256, 4) prep_kernel(
    const int* __restrict__ src, const int* __restrict__ dst,
    const float* __restrict__ dist, int* __restrict__ counts, u32* __restrict__ bucket,
    const float* __restrict__ state, const float* __restrict__ weight,
    u32* __restrict__ G, __half* __restrict__ Pd) {
    __shared__ _Float16 At[64 * 72];          // 9 KB  (fp16 state tile, also x source)
    __shared__ char smemB[128 * 72 * 2];      // 18.4 KB: Bt, then Ps2+Ps
    _Float16* Bt = (_Float16*)smemB;                        // [128][72]
    unsigned short* Ps2 = (unsigned short*)smemB;           // [64][68] p_src
    unsigned short* Ps  = (unsigned short*)(smemB + 8704);  // [64][64] p_dst
    int bid = blockIdx.x;
    int tid = threadIdx.x;

    // ---- edge scatter: 128 edges per block (1250*128 == N_EDGES) ----
    int s_e, d_e; float di_e;
    bool do_edge = tid < 128;
    if (do_edge) {
        int e = bid * 128 + tid;
        s_e = src[e];
        d_e = dst[e];
        di_e = dist[e];
    }

    // ---- proj staging ----
    int row0 = bid * 64;
    int wave = tid >> 6, lane = tid & 63;
    int quad = lane >> 4, m16 = lane & 15;
    int m_loc = wave * 16 + m16;

    // stage state tile (read-once stream) -> fp16 LDS
    const f4v* st4 = (const f4v*)(state + (size_t)row0 * 64);
    for (int i = tid; i < 1024; i += 256) {
        int r = i >> 4, c4 = (i & 15) << 2;
        f4v v = __builtin_nontemporal_load(&st4[i]);
        union { short4 s; _Float16 h[4]; } u;
        u.h[0] = (_Float16)v[0]; u.h[1] = (_Float16)v[1];
        u.h[2] = (_Float16)v[2]; u.h[3] = (_Float16)v[3];
        *(short4*)&At[r * 72 + c4] = u.s;
    }
    // stage weight (32 KB, L2-resident across blocks) transposed -> Bt[n][k]
    const f4v* w4 = (const f4v*)weight;
    for (int i = tid; i < 2048; i += 256) {
        int r = i >> 4, c4 = (i & 15) << 2;    // r in [0,128): r = h*64+k
        f4v v = w4[i];
        int h = r >> 6, k = r & 63;
        int nb = h * 64 + c4;
        Bt[(nb + 0) * 72 + k] = (_Float16)v[0];
        Bt[(nb + 1) * 72 + k] = (_Float16)v[1];
        Bt[(nb + 2) * 72 + k] = (_Float16)v[2];
        Bt[(nb + 3) * 72 + k] = (_Float16)v[3];
    }

    // complete the edge scatter (atomic + scattered 4B store) while LDS fills drain
    if (do_edge) {
        int pos = atomicAdd(&counts[d_e], 1);
        if (pos < CAP) {
            unsigned short hd = __half_as_ushort(__float2half_rn(di_e * 1.44269504f));
            bucket[d_e * CAPR + pos] = (u32)s_e | ((u32)hd << 16);
        }
    }
    __syncthreads();

    // hoist all B-fragments into registers; Bt LDS becomes dead after this
    f16x8 bf0[8], bf1[8];
#pragma unroll
    for (int tcol = 0; tcol < 8; tcol++) {
        int n = tcol * 16 + m16;
        bf0[tcol] = *(const f16x8*)&Bt[n * 72 + quad * 8];
        bf1[tcol] = *(const f16x8*)&Bt[n * 72 + 32 + quad * 8];
    }
    f16x8 a0 = *(const f16x8*)&At[m_loc * 72 + quad * 8];
    f16x8 a1 = *(const f16x8*)&At[m_loc * 72 + 32 + quad * 8];
    __syncthreads();   // everyone done with Bt; reuse as Ps2/Ps

#pragma unroll
    for (int tcol = 0; tcol < 8; tcol++) {
        int n = tcol * 16 + m16;
        f32x4 acc = {0.f, 0.f, 0.f, 0.f};
        acc = __builtin_amdgcn_mfma_f32_16x16x32_f16(a0, bf0[tcol], acc, 0, 0, 0);
        acc = __builtin_amdgcn_mfma_f32_16x16x32_f16(a1, bf1[tcol], acc, 0, 0, 0);
#pragma unroll
        for (int r = 0; r < 4; r++) {
            int ml = wave * 16 + quad * 4 + r;
            unsigned short ph = __half_as_ushort(__float2half_rn(acc[r]));
            if (tcol < 4) Ps2[ml * 68 + n] = ph;
            else          Ps[ml * 64 + (n - 64)] = ph;
        }
    }
    __syncthreads();

    // coalesced G write, slice-pair-major planar-quad: float4 per (row, quad)
    const u32* Ps2w = (const u32*)Ps2;
    const u32* Atw = (const u32*)At;
    for (int i = tid; i < 1024; i += 256) {
        int row = i >> 4, q = i & 15;
        int m = row0 + row;
        int b = m & 7;
        size_t base = (size_t)(b >> 1) * (N_NODES * 128)
                    + (size_t)(m >> 3) * 128 + (size_t)(b & 1) * 64;
        u32 p01 = Ps2w[row * 34 + q * 2];
        u32 p23 = Ps2w[row * 34 + q * 2 + 1];
        u32 x01 = Atw[row * 36 + q * 2];
        u32 x23 = Atw[row * 36 + q * 2 + 1];
        float4 v = make_float4(__uint_as_float(p01), __uint_as_float(p23),
                               __uint_as_float(x01), __uint_as_float(x23));
        *(float4*)&G[base + q * 4] = v;
    }
    // coalesced Pd write, slice-pair-major: 512 float4 (8 lanes = one row's 128 B)
    for (int i = tid; i < 512; i += 256) {
        int row = i >> 3, seg = i & 7;
        int m = row0 + row;
        int b = m & 7;
        size_t base = (size_t)(b >> 1) * (N_NODES * 128)
                    + (size_t)(m >> 3) * 128 + (size_t)(b & 1) * 64;
        *(float4*)&Pd[base + seg * 8] = *(const float4*)&Ps[row * 64 + seg * 8];
    }
}

// ---------------- fused segment-softmax + aggregate: 1 (node, slice-pair) per wave ----
// Wave = (node n, bp). Lane l: e = l>>5 (even/odd edge half), sb = (l>>4)&1,
// q = l&15; lane owns d-quad q of slice 2bp+sb. Per 2-edge iteration: one record
// load (2 uniform addrs) + one fully-coalesced 1 KB gather (2x512 B segments) +
// ~14 VALU covering 2 edges x 2 slices x 64 d. No cross-lane reduction except one
// final xor-32 combine of even/odd partials. bp = bid&3 -> per-XCD gather working
// set is one 5.12 MB bp-plane (mostly L2-resident), restoring R0's low FETCH while
// keeping R5's lean VALU. Odd cnt handled by phantom-edge pad-correction
// (ep[cnt] provably zeroed: cnt odd => cnt < CAP, row zero-filled past real count).
__global__ void __launch_bounds__(256) gat_aggregate(
    const u32* __restrict__ G,          // [bp][node][128 words] planar-quad
    const __half* __restrict__ Pds,     // [bp][node][128 halves]
    const int* __restrict__ counts,
    const u32* __restrict__ bucket,
    float* __restrict__ out) {
    int bid = blockIdx.x;
    int bp = bid & 3;                   // slice-pair; bid%8 in {bp, bp+4} -> XCD affinity
    int ng = bid >> 2;                  // 0..2499
    int wave = threadIdx.x >> 6;
    int lane = threadIdx.x & 63;
    int n = ng * 4 + wave;              // 2500 groups x 4 waves = 10000 nodes per bp
    int e = lane >> 5;                  // even/odd edge half
    int off = (lane & 31) * 4;          // word offset in 128-word row: sb*64 + q*4

    const u32* Gbp = G + (size_t)bp * (N_NODES * 128);
    const __half* Pbp = Pds + (size_t)bp * (N_NODES * 128);

    int cnt = counts[n]; if (cnt > CAP) cnt = CAP;
    const u32* ep = bucket + n * CAPR;

    union { double d; __half2 h[2]; } pd;
    pd.d = *(const double*)(Pbp + n * 128 + off);

    const __half2 c06 = __float2half2_rn(0.6f);
    const __half2 c04 = __float2half2_rn(0.4f);
    __half2 zero = __float2half2_rn(0.f);
    __half2 l01 = zero, l23 = zero, o01 = zero, o23 = zero;

    // leaky_relu(0.2) -> *dist(log2e-scaled) -> exp2, all fp16
    auto lrexp = [&](__half2 z, __half2 dd) -> __half2 {
        HC zz, az; zz.h = z;
        az.u = zz.u & 0x7fff7fffu;                       // |z|
        __half2 lk = __hfma2(az.h, c04, __hmul2(z, c06));
        __half2 aa = __hmul2(lk, dd);
        return __halves2half2(hexp2(__low2half(aa)), hexp2(__high2half(aa)));
    };

    int padded = (cnt + 1) & ~1;
    if (padded > 0) {
        u32 r = ep[e];                  // record for edge (0 + e)
        for (int j = 0; j < padded; j += 2) {
            // one-ahead record prefetch; j+2+e <= padded+1 <= 49 < CAPR, always valid
            u32 rn = ep[j + 2 + e];
            const u32* p = Gbp + (size_t)(r & 0xffffu) * 128 + off;
            float4 g = *(const float4*)p;
            __half hd = __ushort_as_half((unsigned short)(r >> 16));
            __half2 dd = __halves2half2(hd, hd);
            union { float4 f; __half2 h[4]; } u; u.f = g;
            __half2 ex;
            ex = lrexp(__hadd2(u.h[0], pd.h[0]), dd);
            l01 = __hadd2(l01, ex); o01 = __hfma2(ex, u.h[2], o01);
            ex = lrexp(__hadd2(u.h[1], pd.h[1]), dd);
            l23 = __hadd2(l23, ex); o23 = __hfma2(ex, u.h[3], o23);
            r = rn;
        }
        if (cnt & 1) {
            // phantom edge (rec=0): contributed ex=1 and x = node0's state on e==1 lanes
            float4 g0 = *(const float4*)(Gbp + off);
            union { float4 f; __half2 h[4]; } u0; u0.f = g0;
            if (e) {
                __half2 one = __float2half2_rn(1.f);
                l01 = __hsub2(l01, one);
                l23 = __hsub2(l23, one);
                o01 = __hsub2(o01, u0.h[2]);
                o23 = __hsub2(o23, u0.h[3]);
            }
        }
    }

    // combine even/odd edge partials: single xor-32 butterfly
    HC c;
    c.u = (u32)__shfl_xor((int)((HC){.h = l01}).u, 32, 64); l01 = __hadd2(l01, c.h);
    c.u = (u32)__shfl_xor((int)((HC){.h = l23}).u, 32, 64); l23 = __hadd2(l23, c.h);
    c.u = (u32)__shfl_xor((int)((HC){.h = o01}).u, 32, 64); o01 = __hadd2(o01, c.h);
    c.u = (u32)__shfl_xor((int)((HC){.h = o23}).u, 32, 64); o23 = __hadd2(o23, c.h);

    if (e == 0) {   // lanes 0..31 write the (node, 2-slice) block: 512 B contiguous
        float4 r;
        if (cnt > 0) {
            r.x = fmaxf(__low2float(o01)  * __builtin_amdgcn_rcpf(__low2float(l01)),  0.f);
            r.y = fmaxf(__high2float(o01) * __builtin_amdgcn_rcpf(__high2float(l01)), 0.f);
            r.z = fmaxf(__low2float(o23)  * __builtin_amdgcn_rcpf(__low2float(l23)),  0.f);
            r.w = fmaxf(__high2float(o23) * __builtin_amdgcn_rcpf(__high2float(l23)), 0.f);
        } else {
            r = make_float4(0.f, 0.f, 0.f, 0.f);
        }
        *(float4*)(out + (size_t)n * BD + bp * 128 + off) = r;
    }
}

extern "C" void kernel_launch(void* const* d_in, const int* in_sizes, int n_in,
                              void* d_out, int out_size, void* d_ws, size_t ws_size,
                              hipStream_t stream) {
    const float* state  = (const float*)d_in[0];
    // d_in[1] = feature (unused by the math)
    const float* weight = (const float*)d_in[2];
    const int*   src    = (const int*)d_in[3];
    const int*   dst    = (const int*)d_in[4];
    const float* dist   = (const float*)d_in[5];

    // workspace layout (16B-aligned head first): total ~33 MB
    u32*    G      = (u32*)d_ws;                              // 4*N*128 u32 = 20.48 MB
    __half* Pd     = (__half*)(G + (size_t)4 * N_NODES * 128);  // 4*N*128 half = 10.24 MB
    u32*    bucket = (u32*)(Pd + (size_t)4 * N_NODES * 128);    // N*CAPR u32 = 2.24 MB
    int*    counts = (int*)(bucket + (size_t)N_NODES * CAPR); // N ints (contiguous after bucket)

    // one memset zeroes bucket (pad records decode as {src=0, hd=0}) and counts
    hipMemsetAsync(bucket, 0, ((size_t)N_NODES * CAPR + N_NODES) * sizeof(u32), stream);
    prep_kernel<<<1250, 256, 0, stream>>>(src, dst, dist, counts, bucket,
                                          state, weight, G, Pd);
    gat_aggregate<<<10000, 256, 0, stream>>>(G, Pd, counts, bucket, (float*)d_out);
}